// Round 2
// baseline (4299.800 us; speedup 1.0000x reference)
//
#include <hip/hip_runtime.h>
#include <hip/hip_bf16.h>

typedef unsigned short u16;
typedef __bf16 bf16x8 __attribute__((ext_vector_type(8)));
typedef float f32x4 __attribute__((ext_vector_type(4)));
typedef unsigned int u32x4 __attribute__((ext_vector_type(4)));

#define DEVI __device__ __forceinline__

// fp32 -> bf16 round-to-nearest-even
DEVI u16 f2b(float f) {
    unsigned int u = __builtin_bit_cast(unsigned int, f);
    unsigned int lsb = (u >> 16) & 1u;
    u += 0x7fffu + lsb;
    return (u16)(u >> 16);
}
DEVI float b2f(u16 b) {
    unsigned int u = ((unsigned int)b) << 16;
    return __builtin_bit_cast(float, u);
}

DEVI float blockReduceSum(float v, float* red, int tid) {
    #pragma unroll
    for (int o = 32; o; o >>= 1) v += __shfl_xor(v, o);
    __syncthreads();
    if ((tid & 63) == 0) red[tid >> 6] = v;
    __syncthreads();
    return red[0] + red[1] + red[2] + red[3];
}

// ---------------------------------------------------------------------------
// Detect input dtype: flag=1 if float inputs are bf16, 0 if fp32.
// Even-slot u16s of a bf16 buffer decode to |v|<1 (token_emb ~ N(0,0.02));
// of an fp32 buffer they are mantissa bits -> huge/NaN with prob ~1.
// ---------------------------------------------------------------------------
__global__ void detect_kernel(const void* tok, int* flag) {
    __shared__ int bad;
    if (threadIdx.x == 0) bad = 0;
    __syncthreads();
    const u16* p = (const u16*)tok;
    int cnt = 0;
    for (int j = 0; j < 16; ++j) {
        float v = b2f(p[2 * (threadIdx.x * 16 + j)]);
        if (!(fabsf(v) < 1.0f)) cnt++;   // catches NaN too
    }
    if (cnt) atomicAdd(&bad, 1);
    __syncthreads();
    if (threadIdx.x == 0) flag[0] = (bad == 0) ? 1 : 0;
}

__global__ void to_f32_kernel(const void* src, float* dst, int n, const int* flag) {
    int i = blockIdx.x * 256 + threadIdx.x;
    if (i >= n) return;
    if (flag[0]) dst[i] = b2f(((const u16*)src)[i]);
    else         dst[i] = ((const float*)src)[i];
}

// ---------------------------------------------------------------------------
// Core bf16 GEMM: C(M,N) += A(M,K,lda) @ Bt(N,K,ldb)^T, BK=32, wave tile 64x64
// ---------------------------------------------------------------------------
template<int BM, int BN, int NT>
DEVI void gemm_core(const u16* __restrict__ A, int lda,
                    const u16* __restrict__ Bt, int ldb,
                    int K, f32x4 (&acc)[4][4],
                    u16* As, u16* Bs)
{
    const int tid  = threadIdx.x;
    const int lane = tid & 63;
    const int wave = tid >> 6;
    constexpr int WN = BN / 64;
    const int wm   = wave / WN;
    const int wn   = wave % WN;
    const int quad = lane >> 4;
    const int l16  = lane & 15;
    constexpr int ACH = (BM * 4) / NT;
    constexpr int BCH = (BN * 4) / NT;

    for (int k0 = 0; k0 < K; k0 += 32) {
        u32x4 av[ACH], bv[BCH];
        #pragma unroll
        for (int i = 0; i < ACH; ++i) {
            int id = i * NT + tid;
            av[i] = *(const u32x4*)(A + (size_t)(id >> 2) * lda + k0 + (id & 3) * 8);
        }
        #pragma unroll
        for (int i = 0; i < BCH; ++i) {
            int id = i * NT + tid;
            bv[i] = *(const u32x4*)(Bt + (size_t)(id >> 2) * ldb + k0 + (id & 3) * 8);
        }
        __syncthreads();
        #pragma unroll
        for (int i = 0; i < ACH; ++i) { int id = i * NT + tid; *(u32x4*)(As + id * 8) = av[i]; }
        #pragma unroll
        for (int i = 0; i < BCH; ++i) { int id = i * NT + tid; *(u32x4*)(Bs + id * 8) = bv[i]; }
        __syncthreads();

        bf16x8 af[4], bfv[4];
        #pragma unroll
        for (int mt = 0; mt < 4; ++mt)
            af[mt] = *(const bf16x8*)(As + (wm * 64 + mt * 16 + l16) * 32 + quad * 8);
        #pragma unroll
        for (int nt = 0; nt < 4; ++nt)
            bfv[nt] = *(const bf16x8*)(Bs + (wn * 64 + nt * 16 + l16) * 32 + quad * 8);
        #pragma unroll
        for (int mt = 0; mt < 4; ++mt)
            #pragma unroll
            for (int nt = 0; nt < 4; ++nt)
                acc[mt][nt] = __builtin_amdgcn_mfma_f32_16x16x32_bf16(af[mt], bfv[nt], acc[mt][nt], 0, 0, 0);
    }
}

// EPI: 0 = bf16 out (+bias), 1 = bf16 relu (+bias), 2 = fp32 residual add (+bias)
template<int EPI>
__global__ __launch_bounds__(256) void gemm_std(
    const u16* __restrict__ A, int lda,
    const u16* __restrict__ Bt, int ldb,
    const float* __restrict__ bias,
    u16* __restrict__ outB, float* __restrict__ resid,
    int ldc, int K)
{
    __shared__ u16 As[128 * 32];
    __shared__ u16 Bs[128 * 32];
    const size_t bM = (size_t)blockIdx.y * 128;
    const size_t bN = (size_t)blockIdx.x * 128;
    f32x4 acc[4][4] = {};
    gemm_core<128, 128, 256>(A + bM * lda, lda, Bt + bN * ldb, ldb, K, acc, As, Bs);

    const int tid = threadIdx.x, lane = tid & 63, wave = tid >> 6;
    const int wm = wave >> 1, wn = wave & 1, quad = lane >> 4, l16 = lane & 15;
    #pragma unroll
    for (int mt = 0; mt < 4; ++mt)
        #pragma unroll
        for (int nt = 0; nt < 4; ++nt) {
            size_t col = bN + wn * 64 + nt * 16 + l16;
            float bcol = bias[col];
            #pragma unroll
            for (int r = 0; r < 4; ++r) {
                size_t row = bM + wm * 64 + mt * 16 + quad * 4 + r;
                float v = acc[mt][nt][r] + bcol;
                if constexpr (EPI == 1) v = fmaxf(v, 0.f);
                if constexpr (EPI == 2) resid[row * ldc + col] += v;
                else                    outB[row * ldc + col] = f2b(v);
            }
        }
}

// scores[bh, rowL, t] = 0.125 * Q.K ; mask==1 -> -1e9 (reference quirk). 128 q-rows/chunk.
__global__ __launch_bounds__(256) void gemm_scores(
    const u16* __restrict__ qkv, const int* __restrict__ mask,
    float* __restrict__ scores, int qc0)
{
    __shared__ u16 As[128 * 32];
    __shared__ u16 Bs[128 * 32];
    const int bh = blockIdx.z;
    const int b = bh / 12, h = bh % 12;
    const u16* A  = qkv + (size_t)(b * 1024 + qc0) * 2304 + h * 192;
    const u16* Bt = qkv + (size_t)(b * 1024 + blockIdx.x * 128) * 2304 + h * 192 + 64;
    f32x4 acc[4][4] = {};
    gemm_core<128, 128, 256>(A, 2304, Bt, 2304, 64, acc, As, Bs);

    const int tid = threadIdx.x, lane = tid & 63, wave = tid >> 6;
    const int wm = wave >> 1, wn = wave & 1, quad = lane >> 4, l16 = lane & 15;
    #pragma unroll
    for (int mt = 0; mt < 4; ++mt)
        #pragma unroll
        for (int nt = 0; nt < 4; ++nt) {
            int col = blockIdx.x * 128 + wn * 64 + nt * 16 + l16;
            bool msk = mask[b * 1024 + col] != 0;
            #pragma unroll
            for (int r = 0; r < 4; ++r) {
                int rowL = wm * 64 + mt * 16 + quad * 4 + r;
                float v = acc[mt][nt][r] * 0.125f;
                if (msk) v = -1e9f;
                scores[((size_t)bh * 128 + rowL) * 1024 + col] = v;
            }
        }
}

// row softmax over 1024 cols; P written bf16 in-place into first half of fp32 row
__global__ __launch_bounds__(256) void softmax_kernel(float* __restrict__ scores)
{
    __shared__ float red[4];
    const size_t row = blockIdx.x;
    float* srow = scores + row * 1024;
    const int tid = threadIdx.x;
    f32x4 v = *(const f32x4*)(srow + tid * 4);
    float m = fmaxf(fmaxf(v[0], v[1]), fmaxf(v[2], v[3]));
    #pragma unroll
    for (int o = 32; o; o >>= 1) m = fmaxf(m, __shfl_xor(m, o));
    if ((tid & 63) == 0) red[tid >> 6] = m;
    __syncthreads();
    m = fmaxf(fmaxf(red[0], red[1]), fmaxf(red[2], red[3]));
    __syncthreads();
    float e0 = __expf(v[0] - m), e1 = __expf(v[1] - m), e2 = __expf(v[2] - m), e3 = __expf(v[3] - m);
    float s4 = e0 + e1 + e2 + e3;
    #pragma unroll
    for (int o = 32; o; o >>= 1) s4 += __shfl_xor(s4, o);
    if ((tid & 63) == 0) red[tid >> 6] = s4;
    __syncthreads();
    float inv = 1.0f / (red[0] + red[1] + red[2] + red[3]);
    u16* prow = (u16*)srow;   // all reads of srow completed before first barrier
    prow[tid * 4 + 0] = f2b(e0 * inv);
    prow[tid * 4 + 1] = f2b(e1 * inv);
    prow[tid * 4 + 2] = f2b(e2 * inv);
    prow[tid * 4 + 3] = f2b(e3 * inv);
}

// att[b, qc0+rowL, h*64+col] = P(128x1024, lda=2048 bf16) @ Vt(64x1024)^T
__global__ __launch_bounds__(128) void gemm_pv(
    const u16* __restrict__ P, const u16* __restrict__ vt,
    u16* __restrict__ attout, int qc0)
{
    __shared__ u16 As[128 * 32];
    __shared__ u16 Bs[64 * 32];
    const int bh = blockIdx.z;
    const int b = bh / 12, h = bh % 12;
    const u16* Ap = P + (size_t)bh * 128 * 2048;
    const u16* Bt = vt + (size_t)bh * 64 * 1024;
    f32x4 acc[4][4] = {};
    gemm_core<128, 64, 128>(Ap, 2048, Bt, 1024, 1024, acc, As, Bs);

    const int tid = threadIdx.x, lane = tid & 63, wave = tid >> 6;
    const int quad = lane >> 4, l16 = lane & 15;
    #pragma unroll
    for (int mt = 0; mt < 4; ++mt)
        #pragma unroll
        for (int nt = 0; nt < 4; ++nt)
            #pragma unroll
            for (int r = 0; r < 4; ++r) {
                int rowL = wave * 64 + mt * 16 + quad * 4 + r;
                int col  = nt * 16 + l16;
                int s    = qc0 + rowL;
                attout[((size_t)(b * 1024 + s)) * 768 + h * 64 + col] = f2b(acc[mt][nt][r]);
            }
}

// x[b,s,:] = (token_emb[id] + pos_emb[s]) * sqrt(768)  (dual dtype)
__global__ __launch_bounds__(256) void embed_kernel(
    const int* __restrict__ ids, const void* __restrict__ tok,
    const void* __restrict__ pos, float* __restrict__ x, const int* __restrict__ flag)
{
    const int e  = blockIdx.x * 256 + threadIdx.x;
    const int bs = e / 192;
    const int d  = (e - bs * 192) * 4;
    const int s  = bs & 1023;
    const int id = ids[bs];
    float t[4], p4[4];
    if (flag[0]) {
        const u16* tb = (const u16*)tok + (size_t)id * 768 + d;
        const u16* pb = (const u16*)pos + (size_t)s  * 768 + d;
        #pragma unroll
        for (int j = 0; j < 4; ++j) { t[j] = b2f(tb[j]); p4[j] = b2f(pb[j]); }
    } else {
        const float* tb = (const float*)tok + (size_t)id * 768 + d;
        const float* pb = (const float*)pos + (size_t)s  * 768 + d;
        #pragma unroll
        for (int j = 0; j < 4; ++j) { t[j] = tb[j]; p4[j] = pb[j]; }
    }
    float* xo = x + (size_t)bs * 768 + d;
    #pragma unroll
    for (int j = 0; j < 4; ++j) xo[j] = (t[j] + p4[j]) * 27.7128129211020f;
}

__global__ __launch_bounds__(256) void layernorm_kernel(
    const float* __restrict__ x, const float* __restrict__ sc,
    const float* __restrict__ bi, u16* __restrict__ out)
{
    __shared__ float red[4];
    const size_t row = blockIdx.x;
    const float* xr = x + row * 768;
    const int tid = threadIdx.x;
    float v0 = xr[tid], v1 = xr[tid + 256], v2 = xr[tid + 512];
    float s = blockReduceSum(v0 + v1 + v2, red, tid);
    float mean = s * (1.0f / 768.0f);
    float d0 = v0 - mean, d1 = v1 - mean, d2 = v2 - mean;
    float q = blockReduceSum(d0 * d0 + d1 * d1 + d2 * d2, red, tid);
    float rstd = rsqrtf(q * (1.0f / 768.0f) + 1e-5f);
    u16* orow = out + row * 768;
    orow[tid]       = f2b(d0 * rstd * sc[tid]       + bi[tid]);
    orow[tid + 256] = f2b(d1 * rstd * sc[tid + 256] + bi[tid + 256]);
    orow[tid + 512] = f2b(d2 * rstd * sc[tid + 512] + bi[tid + 512]);
}

// W (Kd,Nd) [fp32 or bf16 per flag] -> Wt (Nd,Kd) bf16; one layer per launch
__global__ __launch_bounds__(256) void transpose_w_kernel(
    const void* __restrict__ W, size_t off, u16* __restrict__ Wt,
    int Kd, int Nd, const int* __restrict__ flag)
{
    __shared__ u16 tile[32][34];
    const int n0 = blockIdx.x * 32, k0 = blockIdx.y * 32;
    const int tx = threadIdx.x & 31, ty = threadIdx.x >> 5;
    const int fl = flag[0];
    #pragma unroll
    for (int i = 0; i < 4; ++i) {
        size_t idx = off + (size_t)(k0 + ty + i * 8) * Nd + n0 + tx;
        u16 val = fl ? ((const u16*)W)[idx] : f2b(((const float*)W)[idx]);
        tile[ty + i * 8][tx] = val;
    }
    __syncthreads();
    #pragma unroll
    for (int i = 0; i < 4; ++i)
        Wt[(size_t)(n0 + ty + i * 8) * Kd + k0 + tx] = tile[tx][ty + i * 8];
}

// vt[bh, d, t] = qkv[b, t, h*192+128+d]
__global__ __launch_bounds__(256) void build_vt_kernel(
    const u16* __restrict__ qkv, u16* __restrict__ vt)
{
    __shared__ u16 tile[64][72];
    const int bh = blockIdx.y;
    const int b = bh / 12, h = bh % 12;
    const int t0 = blockIdx.x * 64;
    const int tid = threadIdx.x;
    const int tl = tid >> 2;
    const int d4 = (tid & 3) * 16;
    const u16* src = qkv + (size_t)(b * 1024 + t0 + tl) * 2304 + h * 192 + 128 + d4;
    *(u32x4*)(&tile[tl][d4])     = *(const u32x4*)(src);
    *(u32x4*)(&tile[tl][d4 + 8]) = *(const u32x4*)(src + 8);
    __syncthreads();
    const int dd = tid >> 2;
    const int tstart = (tid & 3) * 16;
    union { u16 us[16]; u32x4 v[2]; } pk;
    #pragma unroll
    for (int j = 0; j < 16; ++j) pk.us[j] = tile[tstart + j][dd];
    u16* dst = vt + ((size_t)bh * 64 + dd) * 1024 + t0 + tstart;
    *(u32x4*)(dst)     = pk.v[0];
    *(u32x4*)(dst + 8) = pk.v[1];
}

// pooled = LN(x[:,0,:]); out = pooled @ cls_w + cls_b ; output dtype per flag
__global__ __launch_bounds__(256) void pooled_cls_kernel(
    const float* __restrict__ x, const float* __restrict__ hs, const float* __restrict__ hb,
    const float* __restrict__ cw, const float* __restrict__ cb, void* __restrict__ dout,
    const int* __restrict__ flag)
{
    __shared__ float red[4];
    __shared__ float pooled[768];
    const int b = blockIdx.x;
    const float* xr = x + (size_t)b * 1024 * 768;
    const int tid = threadIdx.x;
    float v0 = xr[tid], v1 = xr[tid + 256], v2 = xr[tid + 512];
    float s = blockReduceSum(v0 + v1 + v2, red, tid);
    float mean = s * (1.0f / 768.0f);
    float d0 = v0 - mean, d1 = v1 - mean, d2 = v2 - mean;
    float q = blockReduceSum(d0 * d0 + d1 * d1 + d2 * d2, red, tid);
    float rstd = rsqrtf(q * (1.0f / 768.0f) + 1e-5f);
    pooled[tid]       = d0 * rstd * hs[tid]       + hb[tid];
    pooled[tid + 256] = d1 * rstd * hs[tid + 256] + hb[tid + 256];
    pooled[tid + 512] = d2 * rstd * hs[tid + 512] + hb[tid + 512];
    __syncthreads();
    float p0 = 0.f, p1 = 0.f;
    for (int c = tid; c < 768; c += 256) {
        float pv = pooled[c];
        p0 += pv * cw[2 * c];
        p1 += pv * cw[2 * c + 1];
    }
    p0 = blockReduceSum(p0, red, tid);
    p1 = blockReduceSum(p1, red, tid);
    if (tid == 0) {
        float o0 = p0 + cb[0], o1 = p1 + cb[1];
        if (flag[0]) {
            ((u16*)dout)[b * 2 + 0] = f2b(o0);
            ((u16*)dout)[b * 2 + 1] = f2b(o1);
        } else {
            ((float*)dout)[b * 2 + 0] = o0;
            ((float*)dout)[b * 2 + 1] = o1;
        }
    }
}

extern "C" void kernel_launch(void* const* d_in, const int* in_sizes, int n_in,
                              void* d_out, int out_size, void* d_ws, size_t ws_size,
                              hipStream_t stream)
{
    const int* ids  = (const int*)d_in[0];
    const int* mask = (const int*)d_in[1];
    const void* tok   = d_in[2];
    const void* pos   = d_in[3];
    const void* qkv_w = d_in[4];
    const void* qkv_b = d_in[5];
    const void* out_w = d_in[6];
    const void* out_b = d_in[7];
    const void* n1_s  = d_in[8];
    const void* n1_b  = d_in[9];
    const void* ff1_w = d_in[10];
    const void* ff1_b = d_in[11];
    const void* ff2_w = d_in[12];
    const void* ff2_b = d_in[13];
    const void* n2_s  = d_in[14];
    const void* n2_b  = d_in[15];
    const void* hln_s = d_in[16];
    const void* hln_b = d_in[17];
    const void* cls_w = d_in[18];
    const void* cls_b = d_in[19];

    char* p = (char*)d_ws;
    auto alloc = [&](size_t bytes) -> char* {
        char* r = p; p += (bytes + 255) & ~(size_t)255; return r;
    };
    float* x      = (float*)alloc(6291456ull * 4);    // residual (B*S*D) fp32       25.2MB
    u16*   h      = (u16*)  alloc(6291456ull * 2);    // LN out / attout (shared)    12.6MB
    u16*   qkvB   = (u16*)  alloc(18874368ull * 2);   // qkv bf16 (B*S*2304)         37.7MB
    u16*   vt     = (u16*)  alloc(6291456ull * 2);    // V^T (96,64,1024)            12.6MB
    float* scores = (float*)alloc(12582912ull * 4);   // (96,128,1024) fp32          50.3MB
    u16*   wqkvT  = (u16*)  alloc(1769472ull * 2);    // (2304,768) one layer
    u16*   woutT  = (u16*)  alloc(589824ull * 2);     // (768,768)
    u16*   wff1T  = (u16*)  alloc(2359296ull * 2);    // (3072,768)
    u16*   wff2T  = (u16*)  alloc(2359296ull * 2);    // (768,3072)
    float* params = (float*)alloc(62978ull * 4);      // converted fp32 param vectors
    int*   flag   = (int*)  alloc(256);
    u16*   attout = h;                                 // aliases h (disjoint lifetime)
    u16*   ffmid  = (u16*)scores;                      // (8192,3072) bf16 == 50.3MB exact

    // converted-param offsets
    float* P_qkv_b = params + 0;       // 13824
    float* P_out_b = params + 13824;   // 4608
    float* P_n1_s  = params + 18432;   // 4608
    float* P_n1_b  = params + 23040;   // 4608
    float* P_ff1_b = params + 27648;   // 18432
    float* P_ff2_b = params + 46080;   // 4608
    float* P_n2_s  = params + 50688;   // 4608
    float* P_n2_b  = params + 55296;   // 4608
    float* P_hln_s = params + 59904;   // 768
    float* P_hln_b = params + 60672;   // 768
    float* P_cls_w = params + 61440;   // 1536
    float* P_cls_b = params + 62976;   // 2

    detect_kernel<<<1, 256, 0, stream>>>(tok, flag);

    auto cvt = [&](const void* src, float* dst, int n) {
        to_f32_kernel<<<(n + 255) / 256, 256, 0, stream>>>(src, dst, n, flag);
    };
    cvt(qkv_b, P_qkv_b, 13824);  cvt(out_b, P_out_b, 4608);
    cvt(n1_s,  P_n1_s,  4608);   cvt(n1_b,  P_n1_b,  4608);
    cvt(ff1_b, P_ff1_b, 18432);  cvt(ff2_b, P_ff2_b, 4608);
    cvt(n2_s,  P_n2_s,  4608);   cvt(n2_b,  P_n2_b,  4608);
    cvt(hln_s, P_hln_s, 768);    cvt(hln_b, P_hln_b, 768);
    cvt(cls_w, P_cls_w, 1536);   cvt(cls_b, P_cls_b, 2);

    embed_kernel<<<6144, 256, 0, stream>>>(ids, tok, pos, x, flag);

    for (int l = 0; l < 6; ++l) {
        transpose_w_kernel<<<dim3(72, 24), 256, 0, stream>>>(qkv_w, (size_t)l * 1769472, wqkvT, 768, 2304, flag);
        transpose_w_kernel<<<dim3(24, 24), 256, 0, stream>>>(out_w, (size_t)l * 589824,  woutT, 768, 768,  flag);
        transpose_w_kernel<<<dim3(96, 24), 256, 0, stream>>>(ff1_w, (size_t)l * 2359296, wff1T, 768, 3072, flag);
        transpose_w_kernel<<<dim3(24, 96), 256, 0, stream>>>(ff2_w, (size_t)l * 2359296, wff2T, 3072, 768, flag);

        layernorm_kernel<<<8192, 256, 0, stream>>>(x, P_n1_s + l * 768, P_n1_b + l * 768, h);
        gemm_std<0><<<dim3(18, 64), 256, 0, stream>>>(h, 768, wqkvT, 768,
                                                      P_qkv_b + l * 2304, qkvB, nullptr, 2304, 768);
        build_vt_kernel<<<dim3(16, 96), 256, 0, stream>>>(qkvB, vt);
        for (int qc = 0; qc < 8; ++qc) {
            gemm_scores<<<dim3(8, 1, 96), 256, 0, stream>>>(qkvB, mask, scores, qc * 128);
            softmax_kernel<<<12288, 256, 0, stream>>>(scores);
            gemm_pv<<<dim3(1, 1, 96), 128, 0, stream>>>((const u16*)scores, vt, attout, qc * 128);
        }
        gemm_std<2><<<dim3(6, 64), 256, 0, stream>>>(attout, 768, woutT, 768,
                                                     P_out_b + l * 768, nullptr, x, 768, 768);
        layernorm_kernel<<<8192, 256, 0, stream>>>(x, P_n2_s + l * 768, P_n2_b + l * 768, h);
        gemm_std<1><<<dim3(24, 64), 256, 0, stream>>>(h, 768, wff1T, 768,
                                                      P_ff1_b + l * 3072, ffmid, nullptr, 3072, 768);
        gemm_std<2><<<dim3(6, 64), 256, 0, stream>>>(ffmid, 3072, wff2T, 3072,
                                                     P_ff2_b + l * 768, nullptr, x, 768, 3072);
    }
    pooled_cls_kernel<<<8, 256, 0, stream>>>(x, P_hln_s, P_hln_b, P_cls_w, P_cls_b, d_out, flag);
}

// Round 3
// 2538.221 us; speedup vs baseline: 1.6940x; 1.6940x over previous
//
#include <hip/hip_runtime.h>
#include <hip/hip_bf16.h>

typedef unsigned short u16;
typedef __bf16 bf16x8 __attribute__((ext_vector_type(8)));
typedef float f32x4 __attribute__((ext_vector_type(4)));
typedef unsigned int u32x4 __attribute__((ext_vector_type(4)));

#define DEVI __device__ __forceinline__

// fp32 -> bf16 round-to-nearest-even
DEVI u16 f2b(float f) {
    unsigned int u = __builtin_bit_cast(unsigned int, f);
    unsigned int lsb = (u >> 16) & 1u;
    u += 0x7fffu + lsb;
    return (u16)(u >> 16);
}
DEVI float b2f(u16 b) {
    unsigned int u = ((unsigned int)b) << 16;
    return __builtin_bit_cast(float, u);
}

DEVI float blockReduceSum(float v, float* red, int tid) {
    #pragma unroll
    for (int o = 32; o; o >>= 1) v += __shfl_xor(v, o);
    __syncthreads();
    if ((tid & 63) == 0) red[tid >> 6] = v;
    __syncthreads();
    return red[0] + red[1] + red[2] + red[3];
}

// ---------------------------------------------------------------------------
// Detect input dtype: flag=1 if float inputs are bf16, 0 if fp32.
// ---------------------------------------------------------------------------
__global__ void detect_kernel(const void* tok, int* flag) {
    __shared__ int bad;
    if (threadIdx.x == 0) bad = 0;
    __syncthreads();
    const u16* p = (const u16*)tok;
    int cnt = 0;
    for (int j = 0; j < 16; ++j) {
        float v = b2f(p[2 * (threadIdx.x * 16 + j)]);
        if (!(fabsf(v) < 1.0f)) cnt++;
    }
    if (cnt) atomicAdd(&bad, 1);
    __syncthreads();
    if (threadIdx.x == 0) flag[0] = (bad == 0) ? 1 : 0;
}

__global__ void to_f32_kernel(const void* src, float* dst, int n, const int* flag) {
    int i = blockIdx.x * 256 + threadIdx.x;
    if (i >= n) return;
    if (flag[0]) dst[i] = b2f(((const u16*)src)[i]);
    else         dst[i] = ((const float*)src)[i];
}

// ---------------------------------------------------------------------------
// Core bf16 GEMM: C(M,N) += A(M,K,lda) @ Bt(N,K,ldb)^T, BK=32, wave tile 64x64
// LDS rows padded to 40 u16 (20 words) -> 2-way bank aliasing only (free).
// ---------------------------------------------------------------------------
template<int BM, int BN, int NT>
DEVI void gemm_core(const u16* __restrict__ A, int lda,
                    const u16* __restrict__ Bt, int ldb,
                    int K, f32x4 (&acc)[4][4],
                    u16* As, u16* Bs)
{
    const int tid  = threadIdx.x;
    const int lane = tid & 63;
    const int wave = tid >> 6;
    constexpr int WN = BN / 64;
    const int wm   = wave / WN;
    const int wn   = wave % WN;
    const int quad = lane >> 4;
    const int l16  = lane & 15;
    constexpr int ACH = (BM * 4) / NT;
    constexpr int BCH = (BN * 4) / NT;

    for (int k0 = 0; k0 < K; k0 += 32) {
        u32x4 av[ACH], bv[BCH];
        #pragma unroll
        for (int i = 0; i < ACH; ++i) {
            int id = i * NT + tid;
            av[i] = *(const u32x4*)(A + (size_t)(id >> 2) * lda + k0 + (id & 3) * 8);
        }
        #pragma unroll
        for (int i = 0; i < BCH; ++i) {
            int id = i * NT + tid;
            bv[i] = *(const u32x4*)(Bt + (size_t)(id >> 2) * ldb + k0 + (id & 3) * 8);
        }
        __syncthreads();
        #pragma unroll
        for (int i = 0; i < ACH; ++i) { int id = i * NT + tid; *(u32x4*)(As + (id >> 2) * 40 + (id & 3) * 8) = av[i]; }
        #pragma unroll
        for (int i = 0; i < BCH; ++i) { int id = i * NT + tid; *(u32x4*)(Bs + (id >> 2) * 40 + (id & 3) * 8) = bv[i]; }
        __syncthreads();

        bf16x8 af[4], bfv[4];
        #pragma unroll
        for (int mt = 0; mt < 4; ++mt)
            af[mt] = *(const bf16x8*)(As + (wm * 64 + mt * 16 + l16) * 40 + quad * 8);
        #pragma unroll
        for (int nt = 0; nt < 4; ++nt)
            bfv[nt] = *(const bf16x8*)(Bs + (wn * 64 + nt * 16 + l16) * 40 + quad * 8);
        #pragma unroll
        for (int mt = 0; mt < 4; ++mt)
            #pragma unroll
            for (int nt = 0; nt < 4; ++nt)
                acc[mt][nt] = __builtin_amdgcn_mfma_f32_16x16x32_bf16(af[mt], bfv[nt], acc[mt][nt], 0, 0, 0);
    }
}

// EPI: 0 = bf16 out (+bias), 1 = bf16 relu (+bias), 2 = fp32 residual add (+bias)
template<int EPI>
__global__ __launch_bounds__(256) void gemm_std(
    const u16* __restrict__ A, int lda,
    const u16* __restrict__ Bt, int ldb,
    const float* __restrict__ bias,
    u16* __restrict__ outB, float* __restrict__ resid,
    int ldc, int K)
{
    __shared__ u16 As[128 * 40];
    __shared__ u16 Bs[128 * 40];
    const size_t bM = (size_t)blockIdx.y * 128;
    const size_t bN = (size_t)blockIdx.x * 128;
    f32x4 acc[4][4] = {};
    gemm_core<128, 128, 256>(A + bM * lda, lda, Bt + bN * ldb, ldb, K, acc, As, Bs);

    const int tid = threadIdx.x, lane = tid & 63, wave = tid >> 6;
    const int wm = wave >> 1, wn = wave & 1, quad = lane >> 4, l16 = lane & 15;
    #pragma unroll
    for (int mt = 0; mt < 4; ++mt)
        #pragma unroll
        for (int nt = 0; nt < 4; ++nt) {
            size_t col = bN + wn * 64 + nt * 16 + l16;
            float bcol = bias[col];
            #pragma unroll
            for (int r = 0; r < 4; ++r) {
                size_t row = bM + wm * 64 + mt * 16 + quad * 4 + r;
                float v = acc[mt][nt][r] + bcol;
                if constexpr (EPI == 1) v = fmaxf(v, 0.f);
                if constexpr (EPI == 2) resid[row * ldc + col] += v;
                else                    outB[row * ldc + col] = f2b(v);
            }
        }
}

// ---------------------------------------------------------------------------
// Flash attention: one block = one (b,h) x 128 q-rows. 256 thr (4 waves).
// Wave owns a 32-row strip. Q frags in registers; K/V^T tiles in LDS; online
// softmax in registers; P via wave-private padded LDS tile (C->A layout).
// mask quirk (matches reference): mask==1 -> score = -1e9 (unscaled).
// ---------------------------------------------------------------------------
__global__ __launch_bounds__(256, 2) void flash_attn(
    const u16* __restrict__ qkv, const u16* __restrict__ vt,
    const int* __restrict__ mask, u16* __restrict__ attout)
{
    __shared__ u16 Ks[128 * 72];    // 128 keys x 64 d, stride 72
    __shared__ u16 Vs[64 * 136];    // 64 d x 128 keys, stride 136
    __shared__ u16 Ps[128 * 136];   // 128 q x 128 keys, stride 136 (wave-private strips)
    __shared__ float Ms[1024];

    const int bh = blockIdx.y;
    const int b = bh / 12, h = bh % 12;
    const int q0 = blockIdx.x * 128;
    const int tid = threadIdx.x, lane = tid & 63, wave = tid >> 6;
    const int quad = lane >> 4, l16 = lane & 15;

    for (int i = tid; i < 1024; i += 256)
        Ms[i] = (mask[b * 1024 + i] != 0) ? 1.f : 0.f;

    // Q frags: A[m=l16][k=quad*8+j], rows wave*32+mt*16+l16, k-steps s*32
    bf16x8 aq[2][2];
    #pragma unroll
    for (int mt = 0; mt < 2; ++mt)
        #pragma unroll
        for (int s = 0; s < 2; ++s)
            aq[mt][s] = *(const bf16x8*)(qkv + (size_t)(b * 1024 + q0 + wave * 32 + mt * 16 + l16) * 2304
                                          + h * 192 + s * 32 + quad * 8);

    float mi[2][4], li[2][4];
    f32x4 Oacc[2][4] = {};
    #pragma unroll
    for (int mt = 0; mt < 2; ++mt)
        #pragma unroll
        for (int r = 0; r < 4; ++r) { mi[mt][r] = -3e38f; li[mt][r] = 0.f; }

    for (int kt = 0; kt < 8; ++kt) {
        // stage K tile (128 rows x 64 u16 = 1024 x 16B chunks) and V^T tile (64 x 128 u16)
        u32x4 kreg[4], vreg[4];
        #pragma unroll
        for (int i = 0; i < 4; ++i) {
            int id = i * 256 + tid, row = id >> 3, ch = id & 7;
            kreg[i] = *(const u32x4*)(qkv + (size_t)(b * 1024 + kt * 128 + row) * 2304 + h * 192 + 64 + ch * 8);
        }
        #pragma unroll
        for (int i = 0; i < 4; ++i) {
            int id = i * 256 + tid, row = id >> 4, ch = id & 15;
            vreg[i] = *(const u32x4*)(vt + (size_t)bh * 65536 + (size_t)row * 1024 + kt * 128 + ch * 8);
        }
        __syncthreads();   // prior iter's LDS reads (S + PV) done before overwrite
        #pragma unroll
        for (int i = 0; i < 4; ++i) {
            int id = i * 256 + tid, row = id >> 3, ch = id & 7;
            *(u32x4*)(Ks + row * 72 + ch * 8) = kreg[i];
        }
        #pragma unroll
        for (int i = 0; i < 4; ++i) {
            int id = i * 256 + tid, row = id >> 4, ch = id & 15;
            *(u32x4*)(Vs + row * 136 + ch * 8) = vreg[i];
        }
        __syncthreads();

        // S = Q @ K^T : wave computes 32 rows x 128 cols
        f32x4 Sacc[2][8] = {};
        #pragma unroll
        for (int s = 0; s < 2; ++s) {
            bf16x8 kf[8];
            #pragma unroll
            for (int nt = 0; nt < 8; ++nt)
                kf[nt] = *(const bf16x8*)(Ks + (nt * 16 + l16) * 72 + s * 32 + quad * 8);
            #pragma unroll
            for (int mt = 0; mt < 2; ++mt)
                #pragma unroll
                for (int nt = 0; nt < 8; ++nt)
                    Sacc[mt][nt] = __builtin_amdgcn_mfma_f32_16x16x32_bf16(aq[mt][s], kf[nt], Sacc[mt][nt], 0, 0, 0);
        }

        // mask + scale
        float mval[8];
        #pragma unroll
        for (int nt = 0; nt < 8; ++nt) mval[nt] = Ms[kt * 128 + nt * 16 + l16];
        #pragma unroll
        for (int mt = 0; mt < 2; ++mt)
            #pragma unroll
            for (int nt = 0; nt < 8; ++nt)
                #pragma unroll
                for (int r = 0; r < 4; ++r)
                    Sacc[mt][nt][r] = (mval[nt] != 0.f) ? -1e9f : Sacc[mt][nt][r] * 0.125f;

        // online softmax per row (rows: wave*32 + mt*16 + quad*4 + r)
        #pragma unroll
        for (int mt = 0; mt < 2; ++mt) {
            float al[4];
            #pragma unroll
            for (int r = 0; r < 4; ++r) {
                float rm = -3e38f;
                #pragma unroll
                for (int nt = 0; nt < 8; ++nt) rm = fmaxf(rm, Sacc[mt][nt][r]);
                #pragma unroll
                for (int o = 8; o; o >>= 1) rm = fmaxf(rm, __shfl_xor(rm, o));
                float mn = fmaxf(mi[mt][r], rm);
                al[r] = __expf(mi[mt][r] - mn);
                mi[mt][r] = mn;
                float rs = 0.f;
                #pragma unroll
                for (int nt = 0; nt < 8; ++nt) {
                    float pv = __expf(Sacc[mt][nt][r] - mn);
                    rs += pv;
                    Sacc[mt][nt][r] = pv;
                }
                #pragma unroll
                for (int o = 8; o; o >>= 1) rs += __shfl_xor(rs, o);
                li[mt][r] = li[mt][r] * al[r] + rs;
            }
            #pragma unroll
            for (int ntv = 0; ntv < 4; ++ntv)
                #pragma unroll
                for (int r = 0; r < 4; ++r) Oacc[mt][ntv][r] *= al[r];
            // write P (bf16) to wave-private strip of Ps
            const int rowb = wave * 32 + mt * 16 + quad * 4;
            #pragma unroll
            for (int nt = 0; nt < 8; ++nt)
                #pragma unroll
                for (int r = 0; r < 4; ++r)
                    Ps[(rowb + r) * 136 + nt * 16 + l16] = f2b(Sacc[mt][nt][r]);
        }

        // O += P @ V : wave's 32 rows x 64 d; contraction over 128 keys
        #pragma unroll
        for (int s2 = 0; s2 < 4; ++s2) {
            bf16x8 vf[4];
            #pragma unroll
            for (int ntv = 0; ntv < 4; ++ntv)
                vf[ntv] = *(const bf16x8*)(Vs + (ntv * 16 + l16) * 136 + s2 * 32 + quad * 8);
            #pragma unroll
            for (int mt2 = 0; mt2 < 2; ++mt2) {
                bf16x8 pf = *(const bf16x8*)(Ps + (wave * 32 + mt2 * 16 + l16) * 136 + s2 * 32 + quad * 8);
                #pragma unroll
                for (int ntv = 0; ntv < 4; ++ntv)
                    Oacc[mt2][ntv] = __builtin_amdgcn_mfma_f32_16x16x32_bf16(pf, vf[ntv], Oacc[mt2][ntv], 0, 0, 0);
            }
        }
    }

    // epilogue: divide by l, store bf16
    #pragma unroll
    for (int mt = 0; mt < 2; ++mt)
        #pragma unroll
        for (int r = 0; r < 4; ++r) {
            float inv = 1.0f / li[mt][r];
            int s = q0 + wave * 32 + mt * 16 + quad * 4 + r;
            #pragma unroll
            for (int ntv = 0; ntv < 4; ++ntv)
                attout[((size_t)(b * 1024 + s)) * 768 + h * 64 + ntv * 16 + l16] = f2b(Oacc[mt][ntv][r] * inv);
        }
}

// x[b,s,:] = (token_emb[id] + pos_emb[s]) * sqrt(768)  (dual dtype)
__global__ __launch_bounds__(256) void embed_kernel(
    const int* __restrict__ ids, const void* __restrict__ tok,
    const void* __restrict__ pos, float* __restrict__ x, const int* __restrict__ flag)
{
    const int e  = blockIdx.x * 256 + threadIdx.x;
    const int bs = e / 192;
    const int d  = (e - bs * 192) * 4;
    const int s  = bs & 1023;
    const int id = ids[bs];
    float t[4], p4[4];
    if (flag[0]) {
        const u16* tb = (const u16*)tok + (size_t)id * 768 + d;
        const u16* pb = (const u16*)pos + (size_t)s  * 768 + d;
        #pragma unroll
        for (int j = 0; j < 4; ++j) { t[j] = b2f(tb[j]); p4[j] = b2f(pb[j]); }
    } else {
        const float* tb = (const float*)tok + (size_t)id * 768 + d;
        const float* pb = (const float*)pos + (size_t)s  * 768 + d;
        #pragma unroll
        for (int j = 0; j < 4; ++j) { t[j] = tb[j]; p4[j] = pb[j]; }
    }
    float* xo = x + (size_t)bs * 768 + d;
    #pragma unroll
    for (int j = 0; j < 4; ++j) xo[j] = (t[j] + p4[j]) * 27.7128129211020f;
}

__global__ __launch_bounds__(256) void layernorm_kernel(
    const float* __restrict__ x, const float* __restrict__ sc,
    const float* __restrict__ bi, u16* __restrict__ out)
{
    __shared__ float red[4];
    const size_t row = blockIdx.x;
    const float* xr = x + row * 768;
    const int tid = threadIdx.x;
    float v0 = xr[tid], v1 = xr[tid + 256], v2 = xr[tid + 512];
    float s = blockReduceSum(v0 + v1 + v2, red, tid);
    float mean = s * (1.0f / 768.0f);
    float d0 = v0 - mean, d1 = v1 - mean, d2 = v2 - mean;
    float q = blockReduceSum(d0 * d0 + d1 * d1 + d2 * d2, red, tid);
    float rstd = rsqrtf(q * (1.0f / 768.0f) + 1e-5f);
    u16* orow = out + row * 768;
    orow[tid]       = f2b(d0 * rstd * sc[tid]       + bi[tid]);
    orow[tid + 256] = f2b(d1 * rstd * sc[tid + 256] + bi[tid + 256]);
    orow[tid + 512] = f2b(d2 * rstd * sc[tid + 512] + bi[tid + 512]);
}

// W (Kd,Nd) [fp32 or bf16 per flag] -> Wt (Nd,Kd) bf16; one layer per launch
__global__ __launch_bounds__(256) void transpose_w_kernel(
    const void* __restrict__ W, size_t off, u16* __restrict__ Wt,
    int Kd, int Nd, const int* __restrict__ flag)
{
    __shared__ u16 tile[32][34];
    const int n0 = blockIdx.x * 32, k0 = blockIdx.y * 32;
    const int tx = threadIdx.x & 31, ty = threadIdx.x >> 5;
    const int fl = flag[0];
    #pragma unroll
    for (int i = 0; i < 4; ++i) {
        size_t idx = off + (size_t)(k0 + ty + i * 8) * Nd + n0 + tx;
        u16 val = fl ? ((const u16*)W)[idx] : f2b(((const float*)W)[idx]);
        tile[ty + i * 8][tx] = val;
    }
    __syncthreads();
    #pragma unroll
    for (int i = 0; i < 4; ++i)
        Wt[(size_t)(n0 + ty + i * 8) * Kd + k0 + tx] = tile[tx][ty + i * 8];
}

// vt[bh, d, t] = qkv[b, t, h*192+128+d]
__global__ __launch_bounds__(256) void build_vt_kernel(
    const u16* __restrict__ qkv, u16* __restrict__ vt)
{
    __shared__ u16 tile[64][72];
    const int bh = blockIdx.y;
    const int b = bh / 12, h = bh % 12;
    const int t0 = blockIdx.x * 64;
    const int tid = threadIdx.x;
    const int tl = tid >> 2;
    const int d4 = (tid & 3) * 16;
    const u16* src = qkv + (size_t)(b * 1024 + t0 + tl) * 2304 + h * 192 + 128 + d4;
    *(u32x4*)(&tile[tl][d4])     = *(const u32x4*)(src);
    *(u32x4*)(&tile[tl][d4 + 8]) = *(const u32x4*)(src + 8);
    __syncthreads();
    const int dd = tid >> 2;
    const int tstart = (tid & 3) * 16;
    union { u16 us[16]; u32x4 v[2]; } pk;
    #pragma unroll
    for (int j = 0; j < 16; ++j) pk.us[j] = tile[tstart + j][dd];
    u16* dst = vt + ((size_t)bh * 64 + dd) * 1024 + t0 + tstart;
    *(u32x4*)(dst)     = pk.v[0];
    *(u32x4*)(dst + 8) = pk.v[1];
}

// pooled = LN(x[:,0,:]); out = pooled @ cls_w + cls_b ; output dtype per flag
__global__ __launch_bounds__(256) void pooled_cls_kernel(
    const float* __restrict__ x, const float* __restrict__ hs, const float* __restrict__ hb,
    const float* __restrict__ cw, const float* __restrict__ cb, void* __restrict__ dout,
    const int* __restrict__ flag)
{
    __shared__ float red[4];
    __shared__ float pooled[768];
    const int b = blockIdx.x;
    const float* xr = x + (size_t)b * 1024 * 768;
    const int tid = threadIdx.x;
    float v0 = xr[tid], v1 = xr[tid + 256], v2 = xr[tid + 512];
    float s = blockReduceSum(v0 + v1 + v2, red, tid);
    float mean = s * (1.0f / 768.0f);
    float d0 = v0 - mean, d1 = v1 - mean, d2 = v2 - mean;
    float q = blockReduceSum(d0 * d0 + d1 * d1 + d2 * d2, red, tid);
    float rstd = rsqrtf(q * (1.0f / 768.0f) + 1e-5f);
    pooled[tid]       = d0 * rstd * hs[tid]       + hb[tid];
    pooled[tid + 256] = d1 * rstd * hs[tid + 256] + hb[tid + 256];
    pooled[tid + 512] = d2 * rstd * hs[tid + 512] + hb[tid + 512];
    __syncthreads();
    float p0 = 0.f, p1 = 0.f;
    for (int c = tid; c < 768; c += 256) {
        float pv = pooled[c];
        p0 += pv * cw[2 * c];
        p1 += pv * cw[2 * c + 1];
    }
    p0 = blockReduceSum(p0, red, tid);
    p1 = blockReduceSum(p1, red, tid);
    if (tid == 0) {
        float o0 = p0 + cb[0], o1 = p1 + cb[1];
        if (flag[0]) {
            ((u16*)dout)[b * 2 + 0] = f2b(o0);
            ((u16*)dout)[b * 2 + 1] = f2b(o1);
        } else {
            ((float*)dout)[b * 2 + 0] = o0;
            ((float*)dout)[b * 2 + 1] = o1;
        }
    }
}

extern "C" void kernel_launch(void* const* d_in, const int* in_sizes, int n_in,
                              void* d_out, int out_size, void* d_ws, size_t ws_size,
                              hipStream_t stream)
{
    const int* ids  = (const int*)d_in[0];
    const int* mask = (const int*)d_in[1];
    const void* tok   = d_in[2];
    const void* pos   = d_in[3];
    const void* qkv_w = d_in[4];
    const void* qkv_b = d_in[5];
    const void* out_w = d_in[6];
    const void* out_b = d_in[7];
    const void* n1_s  = d_in[8];
    const void* n1_b  = d_in[9];
    const void* ff1_w = d_in[10];
    const void* ff1_b = d_in[11];
    const void* ff2_w = d_in[12];
    const void* ff2_b = d_in[13];
    const void* n2_s  = d_in[14];
    const void* n2_b  = d_in[15];
    const void* hln_s = d_in[16];
    const void* hln_b = d_in[17];
    const void* cls_w = d_in[18];
    const void* cls_b = d_in[19];

    char* p = (char*)d_ws;
    auto alloc = [&](size_t bytes) -> char* {
        char* r = p; p += (bytes + 255) & ~(size_t)255; return r;
    };
    float* x      = (float*)alloc(6291456ull * 4);    // residual (B*S*D) fp32       25.2MB
    u16*   h      = (u16*)  alloc(6291456ull * 2);    // LN out / attout (shared)    12.6MB
    u16*   qkvB   = (u16*)  alloc(18874368ull * 2);   // qkv bf16 (B*S*2304)         37.7MB
    u16*   vt     = (u16*)  alloc(6291456ull * 2);    // V^T (96,64,1024)            12.6MB
    u16*   ffmid  = (u16*)  alloc(25165824ull * 2);   // (8192,3072) bf16            50.3MB
    u16*   wqkvT  = (u16*)  alloc(1769472ull * 2);    // (2304,768) one layer
    u16*   woutT  = (u16*)  alloc(589824ull * 2);     // (768,768)
    u16*   wff1T  = (u16*)  alloc(2359296ull * 2);    // (3072,768)
    u16*   wff2T  = (u16*)  alloc(2359296ull * 2);    // (768,3072)
    float* params = (float*)alloc(62978ull * 4);      // converted fp32 param vectors
    int*   flag   = (int*)  alloc(256);
    u16*   attout = h;                                 // aliases h (disjoint lifetime)

    float* P_qkv_b = params + 0;
    float* P_out_b = params + 13824;
    float* P_n1_s  = params + 18432;
    float* P_n1_b  = params + 23040;
    float* P_ff1_b = params + 27648;
    float* P_ff2_b = params + 46080;
    float* P_n2_s  = params + 50688;
    float* P_n2_b  = params + 55296;
    float* P_hln_s = params + 59904;
    float* P_hln_b = params + 60672;
    float* P_cls_w = params + 61440;
    float* P_cls_b = params + 62976;

    detect_kernel<<<1, 256, 0, stream>>>(tok, flag);

    auto cvt = [&](const void* src, float* dst, int n) {
        to_f32_kernel<<<(n + 255) / 256, 256, 0, stream>>>(src, dst, n, flag);
    };
    cvt(qkv_b, P_qkv_b, 13824);  cvt(out_b, P_out_b, 4608);
    cvt(n1_s,  P_n1_s,  4608);   cvt(n1_b,  P_n1_b,  4608);
    cvt(ff1_b, P_ff1_b, 18432);  cvt(ff2_b, P_ff2_b, 4608);
    cvt(n2_s,  P_n2_s,  4608);   cvt(n2_b,  P_n2_b,  4608);
    cvt(hln_s, P_hln_s, 768);    cvt(hln_b, P_hln_b, 768);
    cvt(cls_w, P_cls_w, 1536);   cvt(cls_b, P_cls_b, 2);

    embed_kernel<<<6144, 256, 0, stream>>>(ids, tok, pos, x, flag);

    for (int l = 0; l < 6; ++l) {
        transpose_w_kernel<<<dim3(72, 24), 256, 0, stream>>>(qkv_w, (size_t)l * 1769472, wqkvT, 768, 2304, flag);
        transpose_w_kernel<<<dim3(24, 24), 256, 0, stream>>>(out_w, (size_t)l * 589824,  woutT, 768, 768,  flag);
        transpose_w_kernel<<<dim3(96, 24), 256, 0, stream>>>(ff1_w, (size_t)l * 2359296, wff1T, 768, 3072, flag);
        transpose_w_kernel<<<dim3(24, 96), 256, 0, stream>>>(ff2_w, (size_t)l * 2359296, wff2T, 3072, 768, flag);

        layernorm_kernel<<<8192, 256, 0, stream>>>(x, P_n1_s + l * 768, P_n1_b + l * 768, h);
        gemm_std<0><<<dim3(18, 64), 256, 0, stream>>>(h, 768, wqkvT, 768,
                                                      P_qkv_b + l * 2304, qkvB, nullptr, 2304, 768);
        build_vt_kernel<<<dim3(16, 96), 256, 0, stream>>>(qkvB, vt);
        flash_attn<<<dim3(8, 96), 256, 0, stream>>>(qkvB, vt, mask, attout);
        gemm_std<2><<<dim3(6, 64), 256, 0, stream>>>(attout, 768, woutT, 768,
                                                     P_out_b + l * 768, nullptr, x, 768, 768);
        layernorm_kernel<<<8192, 256, 0, stream>>>(x, P_n2_s + l * 768, P_n2_b + l * 768, h);
        gemm_std<1><<<dim3(24, 64), 256, 0, stream>>>(h, 768, wff1T, 768,
                                                      P_ff1_b + l * 3072, ffmid, nullptr, 3072, 768);
        gemm_std<2><<<dim3(6, 64), 256, 0, stream>>>(ffmid, 3072, wff2T, 3072,
                                                     P_ff2_b + l * 768, nullptr, x, 768, 3072);
    }
    pooled_cls_kernel<<<8, 256, 0, stream>>>(x, P_hln_s, P_hln_b, P_cls_w, P_cls_b, d_out, flag);
}

// Round 4
// 2528.827 us; speedup vs baseline: 1.7003x; 1.0037x over previous
//
#include <hip/hip_runtime.h>
#include <hip/hip_bf16.h>

typedef unsigned short u16;
typedef __bf16 bf16x8 __attribute__((ext_vector_type(8)));
typedef float f32x4 __attribute__((ext_vector_type(4)));
typedef unsigned int u32x4 __attribute__((ext_vector_type(4)));

#define DEVI __device__ __forceinline__

typedef __attribute__((address_space(3))) void lds_void;
typedef __attribute__((address_space(1))) const void gbl_void;

// async global->LDS, 16B per lane (global_load_lds_dwordx4)
DEVI void gload16(const void* gp, void* lp) {
    __builtin_amdgcn_global_load_lds((gbl_void*)gp, (lds_void*)lp, 16, 0, 0);
}

// fp32 -> bf16 round-to-nearest-even
DEVI u16 f2b(float f) {
    unsigned int u = __builtin_bit_cast(unsigned int, f);
    unsigned int lsb = (u >> 16) & 1u;
    u += 0x7fffu + lsb;
    return (u16)(u >> 16);
}
DEVI float b2f(u16 b) {
    unsigned int u = ((unsigned int)b) << 16;
    return __builtin_bit_cast(float, u);
}

DEVI float blockReduceSum(float v, float* red, int tid) {
    #pragma unroll
    for (int o = 32; o; o >>= 1) v += __shfl_xor(v, o);
    __syncthreads();
    if ((tid & 63) == 0) red[tid >> 6] = v;
    __syncthreads();
    return red[0] + red[1] + red[2] + red[3];
}

// ---------------------------------------------------------------------------
// Detect input dtype: flag=1 if float inputs are bf16, 0 if fp32.
// ---------------------------------------------------------------------------
__global__ void detect_kernel(const void* tok, int* flag) {
    __shared__ int bad;
    if (threadIdx.x == 0) bad = 0;
    __syncthreads();
    const u16* p = (const u16*)tok;
    int cnt = 0;
    for (int j = 0; j < 16; ++j) {
        float v = b2f(p[2 * (threadIdx.x * 16 + j)]);
        if (!(fabsf(v) < 1.0f)) cnt++;
    }
    if (cnt) atomicAdd(&bad, 1);
    __syncthreads();
    if (threadIdx.x == 0) flag[0] = (bad == 0) ? 1 : 0;
}

__global__ void to_f32_kernel(const void* src, float* dst, int n, const int* flag) {
    int i = blockIdx.x * 256 + threadIdx.x;
    if (i >= n) return;
    if (flag[0]) dst[i] = b2f(((const u16*)src)[i]);
    else         dst[i] = ((const float*)src)[i];
}

// ---------------------------------------------------------------------------
// Core bf16 GEMM, async staging (m97 pattern): C(128,128) += A @ Bt^T.
// BK=32; 256 threads; per K-iter each wave issues 2 A- and 2 B-
// global_load_lds_dwordx4 (wave-uniform LDS base + lane*16B, packed rows of
// 32 u16). K % 32 == 0; rows 16B-aligned.
// ---------------------------------------------------------------------------
DEVI void gemm_core_async(const u16* __restrict__ A, int lda,
                          const u16* __restrict__ Bt, int ldb,
                          int K, f32x4 (&acc)[4][4],
                          u16* As, u16* Bs)
{
    const int tid  = threadIdx.x;
    const int lane = tid & 63;
    const int wave = tid >> 6;
    const int quad = lane >> 4;
    const int l16  = lane & 15;
    const int wm   = wave >> 1;
    const int wn   = wave & 1;

    // chunk indices this wave stages: instr i covers chunks (wave*2+i)*64+lane
    const int c0 = (wave * 2 + 0) * 64 + lane;
    const int c1 = (wave * 2 + 1) * 64 + lane;
    const int r0 = c0 >> 2, h0 = (c0 & 3) * 8;
    const int r1 = c1 >> 2, h1 = (c1 & 3) * 8;

    for (int k0 = 0; k0 < K; k0 += 32) {
        __syncthreads();   // prior iter's LDS reads drained before overwrite
        gload16(A  + (size_t)r0 * lda + k0 + h0, As + c0 * 8);
        gload16(Bt + (size_t)r0 * ldb + k0 + h0, Bs + c0 * 8);
        gload16(A  + (size_t)r1 * lda + k0 + h1, As + c1 * 8);
        gload16(Bt + (size_t)r1 * ldb + k0 + h1, Bs + c1 * 8);
        __syncthreads();   // compiler inserts vmcnt(0) drain before barrier

        bf16x8 af[4], bfv[4];
        #pragma unroll
        for (int mt = 0; mt < 4; ++mt)
            af[mt] = *(const bf16x8*)(As + (wm * 64 + mt * 16 + l16) * 32 + quad * 8);
        #pragma unroll
        for (int nt = 0; nt < 4; ++nt)
            bfv[nt] = *(const bf16x8*)(Bs + (wn * 64 + nt * 16 + l16) * 32 + quad * 8);
        #pragma unroll
        for (int mt = 0; mt < 4; ++mt)
            #pragma unroll
            for (int nt = 0; nt < 4; ++nt)
                acc[mt][nt] = __builtin_amdgcn_mfma_f32_16x16x32_bf16(af[mt], bfv[nt], acc[mt][nt], 0, 0, 0);
    }
}

// EPI: 0 = bf16 out (+bias), 1 = bf16 relu (+bias)
template<int EPI>
__global__ __launch_bounds__(256) void gemm_std(
    const u16* __restrict__ A, int lda,
    const u16* __restrict__ Bt, int ldb,
    const float* __restrict__ bias,
    u16* __restrict__ outB, int ldc, int K)
{
    __shared__ u16 As[128 * 32];
    __shared__ u16 Bs[128 * 32];
    const size_t bM = (size_t)blockIdx.y * 128;
    const size_t bN = (size_t)blockIdx.x * 128;
    f32x4 acc[4][4] = {};
    gemm_core_async(A + bM * lda, lda, Bt + bN * ldb, ldb, K, acc, As, Bs);

    const int tid = threadIdx.x, lane = tid & 63, wave = tid >> 6;
    const int wm = wave >> 1, wn = wave & 1, quad = lane >> 4, l16 = lane & 15;
    #pragma unroll
    for (int mt = 0; mt < 4; ++mt)
        #pragma unroll
        for (int nt = 0; nt < 4; ++nt) {
            size_t col = bN + wn * 64 + nt * 16 + l16;
            float bcol = bias[col];
            #pragma unroll
            for (int r = 0; r < 4; ++r) {
                size_t row = bM + wm * 64 + mt * 16 + quad * 4 + r;
                float v = acc[mt][nt][r] + bcol;
                if constexpr (EPI == 1) v = fmaxf(v, 0.f);
                outB[row * ldc + col] = f2b(v);
            }
        }
}

// Split-K GEMM accumulating into fp32 residual via atomicAdd.
// grid.z = split index; bias applied by split 0 only.
__global__ __launch_bounds__(256) void gemm_splitk(
    const u16* __restrict__ A, int lda,
    const u16* __restrict__ Bt, int ldb,
    const float* __restrict__ bias,
    float* __restrict__ resid, int ldc, int Ksub)
{
    __shared__ u16 As[128 * 32];
    __shared__ u16 Bs[128 * 32];
    const size_t bM = (size_t)blockIdx.y * 128;
    const size_t bN = (size_t)blockIdx.x * 128;
    const int Koff = blockIdx.z * Ksub;
    f32x4 acc[4][4] = {};
    gemm_core_async(A + bM * lda + Koff, lda, Bt + bN * ldb + Koff, ldb, Ksub, acc, As, Bs);

    const int tid = threadIdx.x, lane = tid & 63, wave = tid >> 6;
    const int wm = wave >> 1, wn = wave & 1, quad = lane >> 4, l16 = lane & 15;
    const bool addb = (blockIdx.z == 0);
    #pragma unroll
    for (int mt = 0; mt < 4; ++mt)
        #pragma unroll
        for (int nt = 0; nt < 4; ++nt) {
            size_t col = bN + wn * 64 + nt * 16 + l16;
            float bcol = addb ? bias[col] : 0.f;
            #pragma unroll
            for (int r = 0; r < 4; ++r) {
                size_t row = bM + wm * 64 + mt * 16 + quad * 4 + r;
                atomicAdd(&resid[row * ldc + col], acc[mt][nt][r] + bcol);
            }
        }
}

// ---------------------------------------------------------------------------
// Flash attention: one block = one (b,h) x 128 q-rows. 256 thr (4 waves).
// ---------------------------------------------------------------------------
__global__ __launch_bounds__(256, 2) void flash_attn(
    const u16* __restrict__ qkv, const u16* __restrict__ vt,
    const int* __restrict__ mask, u16* __restrict__ attout)
{
    __shared__ u16 Ks[128 * 72];    // 128 keys x 64 d, stride 72
    __shared__ u16 Vs[64 * 136];    // 64 d x 128 keys, stride 136
    __shared__ u16 Ps[128 * 136];   // 128 q x 128 keys (wave-private strips)
    __shared__ float Ms[1024];

    const int bh = blockIdx.y;
    const int b = bh / 12, h = bh % 12;
    const int q0 = blockIdx.x * 128;
    const int tid = threadIdx.x, lane = tid & 63, wave = tid >> 6;
    const int quad = lane >> 4, l16 = lane & 15;

    for (int i = tid; i < 1024; i += 256)
        Ms[i] = (mask[b * 1024 + i] != 0) ? 1.f : 0.f;

    bf16x8 aq[2][2];
    #pragma unroll
    for (int mt = 0; mt < 2; ++mt)
        #pragma unroll
        for (int s = 0; s < 2; ++s)
            aq[mt][s] = *(const bf16x8*)(qkv + (size_t)(b * 1024 + q0 + wave * 32 + mt * 16 + l16) * 2304
                                          + h * 192 + s * 32 + quad * 8);

    float mi[2][4], li[2][4];
    f32x4 Oacc[2][4] = {};
    #pragma unroll
    for (int mt = 0; mt < 2; ++mt)
        #pragma unroll
        for (int r = 0; r < 4; ++r) { mi[mt][r] = -3e38f; li[mt][r] = 0.f; }

    for (int kt = 0; kt < 8; ++kt) {
        u32x4 kreg[4], vreg[4];
        #pragma unroll
        for (int i = 0; i < 4; ++i) {
            int id = i * 256 + tid, row = id >> 3, ch = id & 7;
            kreg[i] = *(const u32x4*)(qkv + (size_t)(b * 1024 + kt * 128 + row) * 2304 + h * 192 + 64 + ch * 8);
        }
        #pragma unroll
        for (int i = 0; i < 4; ++i) {
            int id = i * 256 + tid, row = id >> 4, ch = id & 15;
            vreg[i] = *(const u32x4*)(vt + (size_t)bh * 65536 + (size_t)row * 1024 + kt * 128 + ch * 8);
        }
        __syncthreads();
        #pragma unroll
        for (int i = 0; i < 4; ++i) {
            int id = i * 256 + tid, row = id >> 3, ch = id & 7;
            *(u32x4*)(Ks + row * 72 + ch * 8) = kreg[i];
        }
        #pragma unroll
        for (int i = 0; i < 4; ++i) {
            int id = i * 256 + tid, row = id >> 4, ch = id & 15;
            *(u32x4*)(Vs + row * 136 + ch * 8) = vreg[i];
        }
        __syncthreads();

        f32x4 Sacc[2][8] = {};
        #pragma unroll
        for (int s = 0; s < 2; ++s) {
            bf16x8 kf[8];
            #pragma unroll
            for (int nt = 0; nt < 8; ++nt)
                kf[nt] = *(const bf16x8*)(Ks + (nt * 16 + l16) * 72 + s * 32 + quad * 8);
            #pragma unroll
            for (int mt = 0; mt < 2; ++mt)
                #pragma unroll
                for (int nt = 0; nt < 8; ++nt)
                    Sacc[mt][nt] = __builtin_amdgcn_mfma_f32_16x16x32_bf16(aq[mt][s], kf[nt], Sacc[mt][nt], 0, 0, 0);
        }

        float mval[8];
        #pragma unroll
        for (int nt = 0; nt < 8; ++nt) mval[nt] = Ms[kt * 128 + nt * 16 + l16];
        #pragma unroll
        for (int mt = 0; mt < 2; ++mt)
            #pragma unroll
            for (int nt = 0; nt < 8; ++nt)
                #pragma unroll
                for (int r = 0; r < 4; ++r)
                    Sacc[mt][nt][r] = (mval[nt] != 0.f) ? -1e9f : Sacc[mt][nt][r] * 0.125f;

        #pragma unroll
        for (int mt = 0; mt < 2; ++mt) {
            float al[4];
            #pragma unroll
            for (int r = 0; r < 4; ++r) {
                float rm = -3e38f;
                #pragma unroll
                for (int nt = 0; nt < 8; ++nt) rm = fmaxf(rm, Sacc[mt][nt][r]);
                #pragma unroll
                for (int o = 8; o; o >>= 1) rm = fmaxf(rm, __shfl_xor(rm, o));
                float mn = fmaxf(mi[mt][r], rm);
                al[r] = __expf(mi[mt][r] - mn);
                mi[mt][r] = mn;
                float rs = 0.f;
                #pragma unroll
                for (int nt = 0; nt < 8; ++nt) {
                    float pv = __expf(Sacc[mt][nt][r] - mn);
                    rs += pv;
                    Sacc[mt][nt][r] = pv;
                }
                #pragma unroll
                for (int o = 8; o; o >>= 1) rs += __shfl_xor(rs, o);
                li[mt][r] = li[mt][r] * al[r] + rs;
            }
            #pragma unroll
            for (int ntv = 0; ntv < 4; ++ntv)
                #pragma unroll
                for (int r = 0; r < 4; ++r) Oacc[mt][ntv][r] *= al[r];
            const int rowb = wave * 32 + mt * 16 + quad * 4;
            #pragma unroll
            for (int nt = 0; nt < 8; ++nt)
                #pragma unroll
                for (int r = 0; r < 4; ++r)
                    Ps[(rowb + r) * 136 + nt * 16 + l16] = f2b(Sacc[mt][nt][r]);
        }

        #pragma unroll
        for (int s2 = 0; s2 < 4; ++s2) {
            bf16x8 vf[4];
            #pragma unroll
            for (int ntv = 0; ntv < 4; ++ntv)
                vf[ntv] = *(const bf16x8*)(Vs + (ntv * 16 + l16) * 136 + s2 * 32 + quad * 8);
            #pragma unroll
            for (int mt2 = 0; mt2 < 2; ++mt2) {
                bf16x8 pf = *(const bf16x8*)(Ps + (wave * 32 + mt2 * 16 + l16) * 136 + s2 * 32 + quad * 8);
                #pragma unroll
                for (int ntv = 0; ntv < 4; ++ntv)
                    Oacc[mt2][ntv] = __builtin_amdgcn_mfma_f32_16x16x32_bf16(pf, vf[ntv], Oacc[mt2][ntv], 0, 0, 0);
            }
        }
    }

    #pragma unroll
    for (int mt = 0; mt < 2; ++mt)
        #pragma unroll
        for (int r = 0; r < 4; ++r) {
            float inv = 1.0f / li[mt][r];
            int s = q0 + wave * 32 + mt * 16 + quad * 4 + r;
            #pragma unroll
            for (int ntv = 0; ntv < 4; ++ntv)
                attout[((size_t)(b * 1024 + s)) * 768 + h * 64 + ntv * 16 + l16] = f2b(Oacc[mt][ntv][r] * inv);
        }
}

// x[b,s,:] = (token_emb[id] + pos_emb[s]) * sqrt(768)  (dual dtype)
__global__ __launch_bounds__(256) void embed_kernel(
    const int* __restrict__ ids, const void* __restrict__ tok,
    const void* __restrict__ pos, float* __restrict__ x, const int* __restrict__ flag)
{
    const int e  = blockIdx.x * 256 + threadIdx.x;
    const int bs = e / 192;
    const int d  = (e - bs * 192) * 4;
    const int s  = bs & 1023;
    const int id = ids[bs];
    float t[4], p4[4];
    if (flag[0]) {
        const u16* tb = (const u16*)tok + (size_t)id * 768 + d;
        const u16* pb = (const u16*)pos + (size_t)s  * 768 + d;
        #pragma unroll
        for (int j = 0; j < 4; ++j) { t[j] = b2f(tb[j]); p4[j] = b2f(pb[j]); }
    } else {
        const float* tb = (const float*)tok + (size_t)id * 768 + d;
        const float* pb = (const float*)pos + (size_t)s  * 768 + d;
        #pragma unroll
        for (int j = 0; j < 4; ++j) { t[j] = tb[j]; p4[j] = pb[j]; }
    }
    float* xo = x + (size_t)bs * 768 + d;
    #pragma unroll
    for (int j = 0; j < 4; ++j) xo[j] = (t[j] + p4[j]) * 27.7128129211020f;
}

__global__ __launch_bounds__(256) void layernorm_kernel(
    const float* __restrict__ x, const float* __restrict__ sc,
    const float* __restrict__ bi, u16* __restrict__ out)
{
    __shared__ float red[4];
    const size_t row = blockIdx.x;
    const float* xr = x + row * 768;
    const int tid = threadIdx.x;
    float v0 = xr[tid], v1 = xr[tid + 256], v2 = xr[tid + 512];
    float s = blockReduceSum(v0 + v1 + v2, red, tid);
    float mean = s * (1.0f / 768.0f);
    float d0 = v0 - mean, d1 = v1 - mean, d2 = v2 - mean;
    float q = blockReduceSum(d0 * d0 + d1 * d1 + d2 * d2, red, tid);
    float rstd = rsqrtf(q * (1.0f / 768.0f) + 1e-5f);
    u16* orow = out + row * 768;
    orow[tid]       = f2b(d0 * rstd * sc[tid]       + bi[tid]);
    orow[tid + 256] = f2b(d1 * rstd * sc[tid + 256] + bi[tid + 256]);
    orow[tid + 512] = f2b(d2 * rstd * sc[tid + 512] + bi[tid + 512]);
}

// W (Kd,Nd) [fp32 or bf16 per flag] -> Wt (Nd,Kd) bf16; one layer per launch
__global__ __launch_bounds__(256) void transpose_w_kernel(
    const void* __restrict__ W, size_t off, u16* __restrict__ Wt,
    int Kd, int Nd, const int* __restrict__ flag)
{
    __shared__ u16 tile[32][34];
    const int n0 = blockIdx.x * 32, k0 = blockIdx.y * 32;
    const int tx = threadIdx.x & 31, ty = threadIdx.x >> 5;
    const int fl = flag[0];
    #pragma unroll
    for (int i = 0; i < 4; ++i) {
        size_t idx = off + (size_t)(k0 + ty + i * 8) * Nd + n0 + tx;
        u16 val = fl ? ((const u16*)W)[idx] : f2b(((const float*)W)[idx]);
        tile[ty + i * 8][tx] = val;
    }
    __syncthreads();
    #pragma unroll
    for (int i = 0; i < 4; ++i)
        Wt[(size_t)(n0 + ty + i * 8) * Kd + k0 + tx] = tile[tx][ty + i * 8];
}

// vt[bh, d, t] = qkv[b, t, h*192+128+d]
__global__ __launch_bounds__(256) void build_vt_kernel(
    const u16* __restrict__ qkv, u16* __restrict__ vt)
{
    __shared__ u16 tile[64][72];
    const int bh = blockIdx.y;
    const int b = bh / 12, h = bh % 12;
    const int t0 = blockIdx.x * 64;
    const int tid = threadIdx.x;
    const int tl = tid >> 2;
    const int d4 = (tid & 3) * 16;
    const u16* src = qkv + (size_t)(b * 1024 + t0 + tl) * 2304 + h * 192 + 128 + d4;
    *(u32x4*)(&tile[tl][d4])     = *(const u32x4*)(src);
    *(u32x4*)(&tile[tl][d4 + 8]) = *(const u32x4*)(src + 8);
    __syncthreads();
    const int dd = tid >> 2;
    const int tstart = (tid & 3) * 16;
    union { u16 us[16]; u32x4 v[2]; } pk;
    #pragma unroll
    for (int j = 0; j < 16; ++j) pk.us[j] = tile[tstart + j][dd];
    u16* dst = vt + ((size_t)bh * 64 + dd) * 1024 + t0 + tstart;
    *(u32x4*)(dst)     = pk.v[0];
    *(u32x4*)(dst + 8) = pk.v[1];
}

// pooled = LN(x[:,0,:]); out = pooled @ cls_w + cls_b ; output dtype per flag
__global__ __launch_bounds__(256) void pooled_cls_kernel(
    const float* __restrict__ x, const float* __restrict__ hs, const float* __restrict__ hb,
    const float* __restrict__ cw, const float* __restrict__ cb, void* __restrict__ dout,
    const int* __restrict__ flag)
{
    __shared__ float red[4];
    __shared__ float pooled[768];
    const int b = blockIdx.x;
    const float* xr = x + (size_t)b * 1024 * 768;
    const int tid = threadIdx.x;
    float v0 = xr[tid], v1 = xr[tid + 256], v2 = xr[tid + 512];
    float s = blockReduceSum(v0 + v1 + v2, red, tid);
    float mean = s * (1.0f / 768.0f);
    float d0 = v0 - mean, d1 = v1 - mean, d2 = v2 - mean;
    float q = blockReduceSum(d0 * d0 + d1 * d1 + d2 * d2, red, tid);
    float rstd = rsqrtf(q * (1.0f / 768.0f) + 1e-5f);
    pooled[tid]       = d0 * rstd * hs[tid]       + hb[tid];
    pooled[tid + 256] = d1 * rstd * hs[tid + 256] + hb[tid + 256];
    pooled[tid + 512] = d2 * rstd * hs[tid + 512] + hb[tid + 512];
    __syncthreads();
    float p0 = 0.f, p1 = 0.f;
    for (int c = tid; c < 768; c += 256) {
        float pv = pooled[c];
        p0 += pv * cw[2 * c];
        p1 += pv * cw[2 * c + 1];
    }
    p0 = blockReduceSum(p0, red, tid);
    p1 = blockReduceSum(p1, red, tid);
    if (tid == 0) {
        float o0 = p0 + cb[0], o1 = p1 + cb[1];
        if (flag[0]) {
            ((u16*)dout)[b * 2 + 0] = f2b(o0);
            ((u16*)dout)[b * 2 + 1] = f2b(o1);
        } else {
            ((float*)dout)[b * 2 + 0] = o0;
            ((float*)dout)[b * 2 + 1] = o1;
        }
    }
}

extern "C" void kernel_launch(void* const* d_in, const int* in_sizes, int n_in,
                              void* d_out, int out_size, void* d_ws, size_t ws_size,
                              hipStream_t stream)
{
    const int* ids  = (const int*)d_in[0];
    const int* mask = (const int*)d_in[1];
    const void* tok   = d_in[2];
    const void* pos   = d_in[3];
    const void* qkv_w = d_in[4];
    const void* qkv_b = d_in[5];
    const void* out_w = d_in[6];
    const void* out_b = d_in[7];
    const void* n1_s  = d_in[8];
    const void* n1_b  = d_in[9];
    const void* ff1_w = d_in[10];
    const void* ff1_b = d_in[11];
    const void* ff2_w = d_in[12];
    const void* ff2_b = d_in[13];
    const void* n2_s  = d_in[14];
    const void* n2_b  = d_in[15];
    const void* hln_s = d_in[16];
    const void* hln_b = d_in[17];
    const void* cls_w = d_in[18];
    const void* cls_b = d_in[19];

    char* p = (char*)d_ws;
    auto alloc = [&](size_t bytes) -> char* {
        char* r = p; p += (bytes + 255) & ~(size_t)255; return r;
    };
    float* x      = (float*)alloc(6291456ull * 4);    // residual (B*S*D) fp32       25.2MB
    u16*   h      = (u16*)  alloc(6291456ull * 2);    // LN out / attout (shared)    12.6MB
    u16*   qkvB   = (u16*)  alloc(18874368ull * 2);   // qkv bf16 (B*S*2304)         37.7MB
    u16*   vt     = (u16*)  alloc(6291456ull * 2);    // V^T (96,64,1024)            12.6MB
    u16*   ffmid  = (u16*)  alloc(25165824ull * 2);   // (8192,3072) bf16            50.3MB
    u16*   wqkvT  = (u16*)  alloc(1769472ull * 2);    // (2304,768) one layer
    u16*   woutT  = (u16*)  alloc(589824ull * 2);     // (768,768)
    u16*   wff1T  = (u16*)  alloc(2359296ull * 2);    // (3072,768)
    u16*   wff2T  = (u16*)  alloc(2359296ull * 2);    // (768,3072)
    float* params = (float*)alloc(62978ull * 4);      // converted fp32 param vectors
    int*   flag   = (int*)  alloc(256);
    u16*   attout = h;                                 // aliases h (disjoint lifetime)

    float* P_qkv_b = params + 0;
    float* P_out_b = params + 13824;
    float* P_n1_s  = params + 18432;
    float* P_n1_b  = params + 23040;
    float* P_ff1_b = params + 27648;
    float* P_ff2_b = params + 46080;
    float* P_n2_s  = params + 50688;
    float* P_n2_b  = params + 55296;
    float* P_hln_s = params + 59904;
    float* P_hln_b = params + 60672;
    float* P_cls_w = params + 61440;
    float* P_cls_b = params + 62976;

    detect_kernel<<<1, 256, 0, stream>>>(tok, flag);

    auto cvt = [&](const void* src, float* dst, int n) {
        to_f32_kernel<<<(n + 255) / 256, 256, 0, stream>>>(src, dst, n, flag);
    };
    cvt(qkv_b, P_qkv_b, 13824);  cvt(out_b, P_out_b, 4608);
    cvt(n1_s,  P_n1_s,  4608);   cvt(n1_b,  P_n1_b,  4608);
    cvt(ff1_b, P_ff1_b, 18432);  cvt(ff2_b, P_ff2_b, 4608);
    cvt(n2_s,  P_n2_s,  4608);   cvt(n2_b,  P_n2_b,  4608);
    cvt(hln_s, P_hln_s, 768);    cvt(hln_b, P_hln_b, 768);
    cvt(cls_w, P_cls_w, 1536);   cvt(cls_b, P_cls_b, 2);

    embed_kernel<<<6144, 256, 0, stream>>>(ids, tok, pos, x, flag);

    for (int l = 0; l < 6; ++l) {
        transpose_w_kernel<<<dim3(72, 24), 256, 0, stream>>>(qkv_w, (size_t)l * 1769472, wqkvT, 768, 2304, flag);
        transpose_w_kernel<<<dim3(24, 24), 256, 0, stream>>>(out_w, (size_t)l * 589824,  woutT, 768, 768,  flag);
        transpose_w_kernel<<<dim3(96, 24), 256, 0, stream>>>(ff1_w, (size_t)l * 2359296, wff1T, 768, 3072, flag);
        transpose_w_kernel<<<dim3(24, 96), 256, 0, stream>>>(ff2_w, (size_t)l * 2359296, wff2T, 3072, 768, flag);

        layernorm_kernel<<<8192, 256, 0, stream>>>(x, P_n1_s + l * 768, P_n1_b + l * 768, h);
        gemm_std<0><<<dim3(18, 64), 256, 0, stream>>>(h, 768, wqkvT, 768,
                                                      P_qkv_b + l * 2304, qkvB, 2304, 768);
        build_vt_kernel<<<dim3(16, 96), 256, 0, stream>>>(qkvB, vt);
        flash_attn<<<dim3(8, 96), 256, 0, stream>>>(qkvB, vt, mask, attout);
        gemm_splitk<<<dim3(6, 64, 2), 256, 0, stream>>>(attout, 768, woutT, 768,
                                                        P_out_b + l * 768, x, 768, 384);
        layernorm_kernel<<<8192, 256, 0, stream>>>(x, P_n2_s + l * 768, P_n2_b + l * 768, h);
        gemm_std<1><<<dim3(24, 64), 256, 0, stream>>>(h, 768, wff1T, 768,
                                                      P_ff1_b + l * 3072, ffmid, 3072, 768);
        gemm_splitk<<<dim3(6, 64, 2), 256, 0, stream>>>(ffmid, 3072, wff2T, 3072,
                                                        P_ff2_b + l * 768, x, 768, 1536);
    }
    pooled_cls_kernel<<<8, 256, 0, stream>>>(x, P_hln_s, P_hln_b, P_cls_w, P_cls_b, d_out, flag);
}